// Round 7
// baseline (162.279 us; speedup 1.0000x reference)
//
#include <hip/hip_runtime.h>
#include <hip/hip_bf16.h>

typedef unsigned short u16;
typedef unsigned int u32;
typedef unsigned long long u64;
typedef __attribute__((ext_vector_type(8))) short bf16x8;   // 8 bf16 = 4 VGPR
typedef __attribute__((ext_vector_type(8))) float f32x8;    // half of 32x32 C/D
typedef __attribute__((ext_vector_type(2))) unsigned int u32x2;
typedef __attribute__((ext_vector_type(4))) unsigned int u32x4; // NT-load-able
typedef _Float16 h16x2 __attribute__((ext_vector_type(2)));

static __device__ __forceinline__ u16 f2bf(float f) {
    __hip_bfloat16 b = __float2bfloat16(f);   // RNE
    return *(u16*)&b;
}
static __device__ __forceinline__ u16 f2h(float f) {
    _Float16 h = (_Float16)f;                  // RNE
    return __builtin_bit_cast(u16, h);
}

// 16-B direct global->LDS (HW writes to lds base + lane*16; gsrc is per-lane)
static __device__ __forceinline__ void gload_lds16(const void* g, void* l) {
    __builtin_amdgcn_global_load_lds(
        (const __attribute__((address_space(1))) unsigned int*)g,
        (__attribute__((address_space(3))) unsigned int*)l,
        16, 0, 0);
}

// ---------------------------------------------------------------------------
// Budget (R2-R5 probes): fill 44.5 | harness S ~34 | edge 31.1 | node 9.5 |
// build 1.  R6/R7: edge's 31.1 us = 4M random 64-B L3 line touches at ~8.2
// TB/s.  Mechanism: group edges by i into 8 buckets (1.6 MB P-window each)
// and pin bucket b to XCD b via blockIdx&7 (round-robin dispatch heuristic;
// 2048 blocks = full co-residency).  P reads become per-XCD-L2 hits; Q + rec
// streams are nontemporal so they don't evict the P window.  Partition is a
// deterministic 3-dispatch counting sort (per-block ranges reserved exactly
// from per-block histograms -> no overflow possible, any input).
// Packing limits (fine for this fixed problem): i,j < 2^17, e < 2^20.
// R7 fix: __builtin_nontemporal_load needs ext_vector_type, not uint4.
// ---------------------------------------------------------------------------

#define PART_BLOCKS 256

// ---------------------------------------------------------------------------
// Kernel 0: build W1's MFMA fragment table (node-independent) + W2 as fp16.
// wtab flat index = ((ct*4 + ks)*64 + lane)*8 + j  holds (bf16)
//   Wcat[k = ks*16 + (lane>>5)*8 + j][c = ct*32 + (lane&31)]
// ---------------------------------------------------------------------------
__global__ __launch_bounds__(256) void build_wfrag(
    const float* __restrict__ W1, const float* __restrict__ W2,
    u16* __restrict__ wtab)
{
    const int flat = blockIdx.x * 256 + threadIdx.x;
    if (flat < 8192) {
        const int j    = flat & 7;
        const int lane = (flat >> 3) & 63;
        const int ks   = (flat >> 9) & 3;
        const int ct   = flat >> 11;
        const int k = ks * 16 + (lane >> 5) * 8 + j;
        const int c = ct * 32 + (lane & 31);
        const float v = (c < 64) ? W1[(size_t)k * 64 + c]
                                 : W1[(size_t)(64 + k) * 64 + (c - 64)];
        wtab[flat] = f2bf(v);
    } else if (flat < 8256) {
        wtab[flat] = f2h(W2[flat - 8192]);     // w2tab
    }
}

// ---------------------------------------------------------------------------
// Kernel A (MFMA, swapped operands, 2-pass, LDS-staged z): pq[n][c], fp16.
// Unchanged from R5 (measured ~9.5 us vs 8.1 floor).
// ---------------------------------------------------------------------------
__global__ __launch_bounds__(256, 4) void node_mfma(
    const float* __restrict__ z, const u16* __restrict__ wtab,
    const float* __restrict__ b1, u16* __restrict__ pq, int nNodes)
{
    const int lane   = threadIdx.x & 63;
    const int wave   = threadIdx.x >> 6;
    const int l31    = lane & 31;
    const int half   = lane >> 5;
    const int nodeBase = (blockIdx.x * 4 + wave) * 32;
    if (nodeBase >= nNodes) return;

    __shared__ u16 tile[4][4096];          // 8 KB per wave, wave-private
    char* tb = (char*)&tile[wave][0];

    // ---- phase 1: stage 32 z rows (8 KB) via contiguous 1-KB global_load_lds.
    const char* zbase = (const char*)(z + (size_t)nodeBase * 64);
#pragma unroll
    for (int s = 0; s < 8; ++s) {
        const int r  = 4 * s + (lane >> 4);
        const int bb = (lane & 15) * 16;
        const char* gsrc = zbase + (size_t)r * 256 + (bb ^ ((r & 7) << 4));
        gload_lds16(gsrc, tb + s * 1024);
    }
    asm volatile("s_waitcnt vmcnt(0)" ::: "memory");

    // ---- phase 2: Zf[ks][j] = z[nodeBase+l31][ks*16 + half*8 + j] from LDS
    bf16x8 Zf[4];
    const int sw = (l31 & 7) << 4;
#pragma unroll
    for (int ks = 0; ks < 4; ++ks) {
        const int col0 = ks * 64 + half * 32;          // byte col, 32-B aligned
        const float4 v0 = *(const float4*)(tb + l31 * 256 + ((col0 +  0) ^ sw));
        const float4 v1 = *(const float4*)(tb + l31 * 256 + ((col0 + 16) ^ sw));
        Zf[ks][0] = (short)f2bf(v0.x); Zf[ks][1] = (short)f2bf(v0.y);
        Zf[ks][2] = (short)f2bf(v0.z); Zf[ks][3] = (short)f2bf(v0.w);
        Zf[ks][4] = (short)f2bf(v1.x); Zf[ks][5] = (short)f2bf(v1.y);
        Zf[ks][6] = (short)f2bf(v1.z); Zf[ks][7] = (short)f2bf(v1.w);
    }

    const bf16x8* wt = (const bf16x8*)wtab;

    // ---- phase 3: two passes of 2 ct-quadrants each (halves live acc+Wf)
    for (int pass = 0; pass < 2; ++pass) {
        const int ct0 = 2 * pass;

        bf16x8 Wf[2][4];
#pragma unroll
        for (int c2 = 0; c2 < 2; ++c2)
#pragma unroll
            for (int ks = 0; ks < 4; ++ks)
                Wf[c2][ks] = wt[((ct0 + c2) * 4 + ks) * 64 + lane];

        f32x8 acc[2][2];                       // [c2][reghalf 0..7 / 8..15]
#pragma unroll
        for (int c2 = 0; c2 < 2; ++c2) {
            const int ct = ct0 + c2;
            if (ct < 2) {
#pragma unroll
                for (int g = 0; g < 4; ++g) {
                    const float4 bv =
                        *(const float4*)(b1 + ct * 32 + g * 8 + half * 4);
                    acc[c2][g >> 1][4 * (g & 1) + 0] = bv.x;
                    acc[c2][g >> 1][4 * (g & 1) + 1] = bv.y;
                    acc[c2][g >> 1][4 * (g & 1) + 2] = bv.z;
                    acc[c2][g >> 1][4 * (g & 1) + 3] = bv.w;
                }
            } else {
                acc[c2][0] = (f32x8)(0.0f);
                acc[c2][1] = (f32x8)(0.0f);
            }
        }

#pragma unroll
        for (int c2 = 0; c2 < 2; ++c2) {
            typedef __attribute__((ext_vector_type(16))) float f32x16;
            f32x16 a;
#pragma unroll
            for (int r = 0; r < 8; ++r) { a[r] = acc[c2][0][r]; a[8 + r] = acc[c2][1][r]; }
#pragma unroll
            for (int ks = 0; ks < 4; ++ks)
                a = __builtin_amdgcn_mfma_f32_32x32x16_bf16(
                    Wf[c2][ks], Zf[ks], a, 0, 0, 0);
#pragma unroll
            for (int r = 0; r < 8; ++r) { acc[c2][0][r] = a[r]; acc[c2][1][r] = a[8 + r]; }
        }

#pragma unroll
        for (int c2 = 0; c2 < 2; ++c2)
#pragma unroll
            for (int g = 0; g < 4; ++g) {
                const float f0 = acc[c2][g >> 1][4 * (g & 1) + 0];
                const float f1 = acc[c2][g >> 1][4 * (g & 1) + 1];
                const float f2 = acc[c2][g >> 1][4 * (g & 1) + 2];
                const float f3 = acc[c2][g >> 1][4 * (g & 1) + 3];
                const u32 lo = (u32)f2h(f0) | ((u32)f2h(f1) << 16);
                const u32 hi = (u32)f2h(f2) | ((u32)f2h(f3) << 16);
                const int roff = ((ct0 + c2) * 64 + g * 16 + half * 8)
                                 ^ ((l31 & 7) << 4);
                *(u32x2*)(tb + l31 * 256 + roff) = (u32x2){lo, hi};
            }
    }

    // ---- phase 4: coalesced readback + 1 KB/instr global stores
#pragma unroll
    for (int it = 0; it < 8; ++it) {
        const int c16  = lane + 64 * it;       // 16-B chunk id in 8 KB tile
        const int nd   = c16 >> 4;             // node within tile
        const int roff = ((c16 & 15) * 16) ^ ((nd & 7) << 4);
        const uint4 v = *(const uint4*)(tb + nd * 256 + roff);
        if (nodeBase + nd < nNodes)
            *(uint4*)(pq + (size_t)nodeBase * 128 + (size_t)c16 * 8) = v;
    }
}

// ---------------------------------------------------------------------------
// Partition pass 1: per-block, per-bucket histogram.  bucket = i / bdiv.
// ---------------------------------------------------------------------------
__global__ __launch_bounds__(256) void edge_histo(
    const int* __restrict__ e0, u32* __restrict__ cnt, int E, u32 bdiv)
{
    __shared__ u32 h[8];
    if (threadIdx.x < 8) h[threadIdx.x] = 0;
    __syncthreads();
    const int chunk = (E + PART_BLOCKS - 1) / PART_BLOCKS;
    const int start = blockIdx.x * chunk;
    const int end   = min(E, start + chunk);
    for (int idx = start + threadIdx.x; idx < end; idx += 256)
        atomicAdd(&h[(u32)e0[idx] / bdiv], 1u);
    __syncthreads();
    if (threadIdx.x < 8) cnt[blockIdx.x * 8 + threadIdx.x] = h[threadIdx.x];
}

// ---------------------------------------------------------------------------
// Partition pass 2: exclusive scan of cnt[256][8] -> per-block bucket bases.
// One block; 8 Hillis-Steele scans of length 256.
// ---------------------------------------------------------------------------
__global__ __launch_bounds__(256) void edge_scan(
    const u32* __restrict__ cnt, u32* __restrict__ base,
    u32* __restrict__ bucketBase, u32* __restrict__ bucketCnt)
{
    __shared__ u32 arr[256];
    const int t = threadIdx.x;
    u32 acc = 0;                               // uniform across threads
    for (int b = 0; b < 8; ++b) {
        const u32 v = cnt[t * 8 + b];
        arr[t] = v; __syncthreads();
        for (int ofs = 1; ofs < 256; ofs <<= 1) {
            const u32 x = (t >= ofs) ? arr[t - ofs] : 0;
            __syncthreads();
            arr[t] += x; __syncthreads();
        }
        const u32 incl  = arr[t];
        const u32 total = arr[255];
        base[t * 8 + b] = acc + incl - v;      // exclusive within bucket b
        if (t == 0) { bucketBase[b] = acc; bucketCnt[b] = total; }
        acc += total;
        __syncthreads();
    }
}

// ---------------------------------------------------------------------------
// Partition pass 3: scatter packed records into per-block reserved ranges.
// Same chunking as pass 1 -> same edge set per block -> no overflow possible.
// rec = i(17b) | j(17b)<<17 | e(20b)<<34.
// ---------------------------------------------------------------------------
__global__ __launch_bounds__(256) void edge_scatter(
    const int* __restrict__ e0, const int* __restrict__ e1,
    const u32* __restrict__ base, u64* __restrict__ rec, int E, u32 bdiv)
{
    __shared__ u32 cur[8];
    if (threadIdx.x < 8) cur[threadIdx.x] = base[blockIdx.x * 8 + threadIdx.x];
    __syncthreads();
    const int chunk = (E + PART_BLOCKS - 1) / PART_BLOCKS;
    const int start = blockIdx.x * chunk;
    const int end   = min(E, start + chunk);
    for (int idx = start + threadIdx.x; idx < end; idx += 256) {
        const u32 i = (u32)e0[idx];
        const u32 j = (u32)e1[idx];
        const u32 pos = atomicAdd(&cur[i / bdiv], 1u);
        rec[pos] = (u64)i | ((u64)j << 17) | ((u64)idx << 34);
    }
}

// ---------------------------------------------------------------------------
// Kernel B: XCD-affine edge MLP.  bucket = blockIdx&7 (round-robin block->XCD
// heuristic; 2048 blocks x 256 thr = full co-residency).  Per bucket the
// P-window is 12500 rows x 128 B = 1.6 MB -> resident in that XCD's 4-MiB L2.
// Q and rec streams are nontemporal so they do not evict the P window.
// 4 lanes per edge; math identical to previous rounds (absmax unchanged).
// ---------------------------------------------------------------------------
__global__ __launch_bounds__(256) void edge_mlp_part(
    const u64* __restrict__ rec, const u32* __restrict__ bucketBase,
    const u32* __restrict__ bucketCnt, const u16* __restrict__ pq,
    const u16* __restrict__ w2tab, const float* __restrict__ b2,
    float* __restrict__ out)
{
    const u32 b  = blockIdx.x & 7;             // XCD id under round-robin
    const u32 s  = blockIdx.x >> 3;            // 0..255 slice within bucket
    const u32 rb = bucketBase[b];
    const u32 rc = bucketCnt[b];
    const int tid  = threadIdx.x;
    const u32 egrp = (u32)(tid >> 2);
    const int sub  = tid & 3;

    const uint4* wr = (const uint4*)w2tab;     // L1-hot fp16 W2
    const uint4 w0 = wr[2 * sub];
    const uint4 w1 = wr[2 * sub + 1];
    const float bias = b2[0];
    const h16x2 hzero = (h16x2){(_Float16)0.0f, (_Float16)0.0f};

    for (u32 o = s * 64u; o < rc; o += 64u * 256u) {
        const u32 ei = o + egrp;
        if (ei < rc) {
            const u64 r = __builtin_nontemporal_load(
                (const u64*)&rec[rb + ei]);
            const u32 i = (u32)r & 131071u;
            const u32 j = ((u32)(r >> 17)) & 131071u;
            const u32 e = (u32)(r >> 34);

            const uint4* pr = (const uint4*)(pq + (size_t)i * 128);
            const u32x4* qr = (const u32x4*)(pq + (size_t)j * 128 + 64);
            const uint4 p0 = pr[2 * sub];
            const uint4 p1 = pr[2 * sub + 1];
            const u32x4 q0 = __builtin_nontemporal_load(qr + 2 * sub);
            const u32x4 q1 = __builtin_nontemporal_load(qr + 2 * sub + 1);

            const u32 pw[8] = {p0.x, p0.y, p0.z, p0.w, p1.x, p1.y, p1.z, p1.w};
            const u32 qw[8] = {q0[0], q0[1], q0[2], q0[3],
                               q1[0], q1[1], q1[2], q1[3]};
            const u32 ww[8] = {w0.x, w0.y, w0.z, w0.w, w1.x, w1.y, w1.z, w1.w};

            float sum = 0.0f;
#pragma unroll
            for (int c = 0; c < 8; ++c) {
                h16x2 pp = __builtin_bit_cast(h16x2, pw[c]);
                h16x2 qq = __builtin_bit_cast(h16x2, qw[c]);
                h16x2 wc = __builtin_bit_cast(h16x2, ww[c]);
                h16x2 a  = __builtin_elementwise_max(pp + qq, hzero);
#if __has_builtin(__builtin_amdgcn_fdot2)
                sum = __builtin_amdgcn_fdot2(a, wc, sum, false);
#else
                sum = fmaf((float)a[0], (float)wc[0],
                      fmaf((float)a[1], (float)wc[1], sum));
#endif
            }

            sum += __shfl_xor(sum, 1);
            sum += __shfl_xor(sum, 2);

            if (sub == 0) out[e] = sum + bias;
        }
    }
}

// ---------------------------------------------------------------------------
extern "C" void kernel_launch(void* const* d_in, const int* in_sizes, int n_in,
                              void* d_out, int out_size, void* d_ws, size_t ws_size,
                              hipStream_t stream) {
    const float* z  = (const float*)d_in[0];
    const int*   eg = (const int*)d_in[1];
    const float* W1 = (const float*)d_in[2];
    const float* b1 = (const float*)d_in[3];
    const float* W2 = (const float*)d_in[4];
    const float* b2 = (const float*)d_in[5];
    float* out = (float*)d_out;

    const int nNodes = in_sizes[0] / 64;   // 100000
    const int E      = in_sizes[1] / 2;    // 1000000

    char* wsb = (char*)d_ws;
    u16* wtab = (u16*)d_ws;                        // 16 KB frag table + W2
    u16* pq   = (u16*)d_ws + 16384;                // nNodes*128*2 = 25.6 MB
    u64* rec  = (u64*)(wsb + 32768 + (size_t)nNodes * 256);   // E*8 = 8 MB
    u32* cnt  = (u32*)((char*)rec + (size_t)E * 8);           // [256][8]
    u32* base = cnt + PART_BLOCKS * 8;                        // [256][8]
    u32* bucketBase = base + PART_BLOCKS * 8;                 // [8]
    u32* bucketCnt  = bucketBase + 8;                         // [8]

    const u32 bdiv = (u32)((nNodes + 7) / 8);      // 12500

    build_wfrag<<<dim3(33), dim3(256), 0, stream>>>(W1, W2, wtab);

    dim3 gA((nNodes + 127) / 128);         // 4 waves x 32 nodes per block
    node_mfma<<<gA, dim3(256), 0, stream>>>(z, wtab, b1, pq, nNodes);

    edge_histo<<<dim3(PART_BLOCKS), dim3(256), 0, stream>>>(eg, cnt, E, bdiv);
    edge_scan<<<dim3(1), dim3(256), 0, stream>>>(cnt, base, bucketBase, bucketCnt);
    edge_scatter<<<dim3(PART_BLOCKS), dim3(256), 0, stream>>>(
        eg, eg + E, base, rec, E, bdiv);

    edge_mlp_part<<<dim3(2048), dim3(256), 0, stream>>>(
        rec, bucketBase, bucketCnt, pq, wtab + 8192, b2, out);
}

// Round 8
// 121.007 us; speedup vs baseline: 1.3411x; 1.3411x over previous
//
#include <hip/hip_runtime.h>
#include <hip/hip_bf16.h>

typedef unsigned short u16;
typedef unsigned int u32;
typedef __attribute__((ext_vector_type(8))) short bf16x8;   // 8 bf16 = 4 VGPR
typedef __attribute__((ext_vector_type(8))) float f32x8;    // half of 32x32 C/D
typedef __attribute__((ext_vector_type(2))) unsigned int u32x2;
typedef _Float16 h16x2 __attribute__((ext_vector_type(2)));

static __device__ __forceinline__ u16 f2bf(float f) {
    __hip_bfloat16 b = __float2bfloat16(f);   // RNE
    return *(u16*)&b;
}
static __device__ __forceinline__ u16 f2h(float f) {
    _Float16 h = (_Float16)f;                  // RNE
    return __builtin_bit_cast(u16, h);
}

// 16-B direct global->LDS (HW writes to lds base + lane*16; gsrc is per-lane)
static __device__ __forceinline__ void gload_lds16(const void* g, void* l) {
    __builtin_amdgcn_global_load_lds(
        (const __attribute__((address_space(1))) unsigned int*)g,
        (__attribute__((address_space(3))) unsigned int*)l,
        16, 0, 0);
}

// ---------------------------------------------------------------------------
// FINAL (revert to R5 best, 120.59 us).  Session budget, probe-verified:
//   fill 44.5 | harness overhead ~34 | edge 31.1 | node ~9.5 | build ~1.
// Edge is at its L3 random-gather floor (4M mandatory 64-B line touches,
// ~8.2 TB/s effective): per-thread concurrency restructure (R1) was null,
// and the 8-bucket XCD-affinity + NT-stream variant (R7) REGRESSED to 50 us
// because NT loads bypass the Infinity Cache (70 MB HBM fetch/dispatch) and
// scattered out[e] writes amplified write traffic 5x.  Node is within
// ~1.4 us of its stream floor after the occupancy split (R4) and the
// swizzled global_load_lds z-staging (R5).
// ---------------------------------------------------------------------------

// ---------------------------------------------------------------------------
// Kernel 0: build W1's MFMA fragment table (node-independent) + W2 as fp16.
// wtab flat index = ((ct*4 + ks)*64 + lane)*8 + j  holds (bf16)
//   Wcat[k = ks*16 + (lane>>5)*8 + j][c = ct*32 + (lane&31)]
// ---------------------------------------------------------------------------
__global__ __launch_bounds__(256) void build_wfrag(
    const float* __restrict__ W1, const float* __restrict__ W2,
    u16* __restrict__ wtab)
{
    const int flat = blockIdx.x * 256 + threadIdx.x;
    if (flat < 8192) {
        const int j    = flat & 7;
        const int lane = (flat >> 3) & 63;
        const int ks   = (flat >> 9) & 3;
        const int ct   = flat >> 11;
        const int k = ks * 16 + (lane >> 5) * 8 + j;
        const int c = ct * 32 + (lane & 31);
        const float v = (c < 64) ? W1[(size_t)k * 64 + c]
                                 : W1[(size_t)(64 + k) * 64 + (c - 64)];
        wtab[flat] = f2bf(v);
    } else if (flat < 8256) {
        wtab[flat] = f2h(W2[flat - 8192]);     // w2tab
    }
}

// ---------------------------------------------------------------------------
// Kernel A (MFMA, swapped operands, 2-pass, LDS-staged z): pq[n][c], fp16.
//   A = Wcat fragment (M = c), B = z fragment (N = node).
// D layout: col(lane&31)=node, row=(reg&3)+8*(reg>>2)+4*half = c within tile.
// LDS tile (8 KB/wave) lifecycle: [z-stage, swizzled] -> Zf regs ->
// [output pack, swizzled] -> coalesced readback/store.
// Swizzle involution (both layouts): phys(row,b) = row*256 + (b^((row&7)<<4)).
// ---------------------------------------------------------------------------
__global__ __launch_bounds__(256, 4) void node_mfma(
    const float* __restrict__ z, const u16* __restrict__ wtab,
    const float* __restrict__ b1, u16* __restrict__ pq, int nNodes)
{
    const int lane   = threadIdx.x & 63;
    const int wave   = threadIdx.x >> 6;
    const int l31    = lane & 31;
    const int half   = lane >> 5;
    const int nodeBase = (blockIdx.x * 4 + wave) * 32;
    if (nodeBase >= nNodes) return;

    __shared__ u16 tile[4][4096];          // 8 KB per wave, wave-private
    char* tb = (char*)&tile[wave][0];

    // ---- phase 1: stage 32 z rows (8 KB) via contiguous 1-KB global_load_lds.
    const char* zbase = (const char*)(z + (size_t)nodeBase * 64);
#pragma unroll
    for (int s = 0; s < 8; ++s) {
        const int r  = 4 * s + (lane >> 4);
        const int bb = (lane & 15) * 16;
        const char* gsrc = zbase + (size_t)r * 256 + (bb ^ ((r & 7) << 4));
        gload_lds16(gsrc, tb + s * 1024);
    }
    asm volatile("s_waitcnt vmcnt(0)" ::: "memory");

    // ---- phase 2: Zf[ks][j] = z[nodeBase+l31][ks*16 + half*8 + j] from LDS
    bf16x8 Zf[4];
    const int sw = (l31 & 7) << 4;
#pragma unroll
    for (int ks = 0; ks < 4; ++ks) {
        const int col0 = ks * 64 + half * 32;          // byte col, 32-B aligned
        const float4 v0 = *(const float4*)(tb + l31 * 256 + ((col0 +  0) ^ sw));
        const float4 v1 = *(const float4*)(tb + l31 * 256 + ((col0 + 16) ^ sw));
        Zf[ks][0] = (short)f2bf(v0.x); Zf[ks][1] = (short)f2bf(v0.y);
        Zf[ks][2] = (short)f2bf(v0.z); Zf[ks][3] = (short)f2bf(v0.w);
        Zf[ks][4] = (short)f2bf(v1.x); Zf[ks][5] = (short)f2bf(v1.y);
        Zf[ks][6] = (short)f2bf(v1.z); Zf[ks][7] = (short)f2bf(v1.w);
    }

    const bf16x8* wt = (const bf16x8*)wtab;

    // ---- phase 3: two passes of 2 ct-quadrants each (halves live acc+Wf)
    for (int pass = 0; pass < 2; ++pass) {
        const int ct0 = 2 * pass;

        bf16x8 Wf[2][4];
#pragma unroll
        for (int c2 = 0; c2 < 2; ++c2)
#pragma unroll
            for (int ks = 0; ks < 4; ++ks)
                Wf[c2][ks] = wt[((ct0 + c2) * 4 + ks) * 64 + lane];

        f32x8 acc[2][2];                       // [c2][reghalf 0..7 / 8..15]
#pragma unroll
        for (int c2 = 0; c2 < 2; ++c2) {
            const int ct = ct0 + c2;
            if (ct < 2) {
#pragma unroll
                for (int g = 0; g < 4; ++g) {
                    const float4 bv =
                        *(const float4*)(b1 + ct * 32 + g * 8 + half * 4);
                    acc[c2][g >> 1][4 * (g & 1) + 0] = bv.x;
                    acc[c2][g >> 1][4 * (g & 1) + 1] = bv.y;
                    acc[c2][g >> 1][4 * (g & 1) + 2] = bv.z;
                    acc[c2][g >> 1][4 * (g & 1) + 3] = bv.w;
                }
            } else {
                acc[c2][0] = (f32x8)(0.0f);
                acc[c2][1] = (f32x8)(0.0f);
            }
        }

#pragma unroll
        for (int c2 = 0; c2 < 2; ++c2) {
            typedef __attribute__((ext_vector_type(16))) float f32x16;
            f32x16 a;
#pragma unroll
            for (int r = 0; r < 8; ++r) { a[r] = acc[c2][0][r]; a[8 + r] = acc[c2][1][r]; }
#pragma unroll
            for (int ks = 0; ks < 4; ++ks)
                a = __builtin_amdgcn_mfma_f32_32x32x16_bf16(
                    Wf[c2][ks], Zf[ks], a, 0, 0, 0);
#pragma unroll
            for (int r = 0; r < 8; ++r) { acc[c2][0][r] = a[r]; acc[c2][1][r] = a[8 + r]; }
        }

#pragma unroll
        for (int c2 = 0; c2 < 2; ++c2)
#pragma unroll
            for (int g = 0; g < 4; ++g) {
                const float f0 = acc[c2][g >> 1][4 * (g & 1) + 0];
                const float f1 = acc[c2][g >> 1][4 * (g & 1) + 1];
                const float f2 = acc[c2][g >> 1][4 * (g & 1) + 2];
                const float f3 = acc[c2][g >> 1][4 * (g & 1) + 3];
                const u32 lo = (u32)f2h(f0) | ((u32)f2h(f1) << 16);
                const u32 hi = (u32)f2h(f2) | ((u32)f2h(f3) << 16);
                const int roff = ((ct0 + c2) * 64 + g * 16 + half * 8)
                                 ^ ((l31 & 7) << 4);
                *(u32x2*)(tb + l31 * 256 + roff) = (u32x2){lo, hi};
            }
    }

    // ---- phase 4: coalesced readback + 1 KB/instr global stores
#pragma unroll
    for (int it = 0; it < 8; ++it) {
        const int c16  = lane + 64 * it;       // 16-B chunk id in 8 KB tile
        const int nd   = c16 >> 4;             // node within tile
        const int roff = ((c16 & 15) * 16) ^ ((nd & 7) << 4);
        const uint4 v = *(const uint4*)(tb + nd * 256 + roff);
        if (nodeBase + nd < nNodes)
            *(uint4*)(pq + (size_t)nodeBase * 128 + (size_t)c16 * 8) = v;
    }
}

// ---------------------------------------------------------------------------
// Kernel B: edge MLP tail. 4 lanes per edge, 4x16-B gathers per thread.
// At its L3 random-gather floor (31.1 us, ~8.2 TB/s effective).
// ---------------------------------------------------------------------------
__global__ __launch_bounds__(256) void edge_mlp(
    const int* __restrict__ e0, const int* __restrict__ e1,
    const u16* __restrict__ pq, const u16* __restrict__ w2tab,
    const float* __restrict__ b2, float* __restrict__ out, int E)
{
    const int gid = blockIdx.x * 256 + threadIdx.x;
    const int e   = gid >> 2;
    const int sub = gid & 3;
    if (e >= E) return;

    const int i = e0[e];
    const int j = e1[e];

    const uint4* pr = (const uint4*)(pq + (size_t)i * 128);
    const uint4* qr = (const uint4*)(pq + (size_t)j * 128 + 64);
    const uint4 p0 = pr[2 * sub];
    const uint4 p1 = pr[2 * sub + 1];
    const uint4 q0 = qr[2 * sub];
    const uint4 q1 = qr[2 * sub + 1];

    const uint4* wr = (const uint4*)w2tab;     // L1-hot fp16 W2
    const uint4 w0 = wr[2 * sub];
    const uint4 w1 = wr[2 * sub + 1];

    const u32 pw[8] = {p0.x, p0.y, p0.z, p0.w, p1.x, p1.y, p1.z, p1.w};
    const u32 qw[8] = {q0.x, q0.y, q0.z, q0.w, q1.x, q1.y, q1.z, q1.w};
    const u32 ww[8] = {w0.x, w0.y, w0.z, w0.w, w1.x, w1.y, w1.z, w1.w};
    const h16x2 hzero = (h16x2){(_Float16)0.0f, (_Float16)0.0f};

    float sum = 0.0f;
#pragma unroll
    for (int c = 0; c < 8; ++c) {
        h16x2 pp = __builtin_bit_cast(h16x2, pw[c]);
        h16x2 qq = __builtin_bit_cast(h16x2, qw[c]);
        h16x2 wc = __builtin_bit_cast(h16x2, ww[c]);
        h16x2 a  = __builtin_elementwise_max(pp + qq, hzero); // pk_add + pk_max
#if __has_builtin(__builtin_amdgcn_fdot2)
        sum = __builtin_amdgcn_fdot2(a, wc, sum, false);
#else
        sum = fmaf((float)a[0], (float)wc[0],
              fmaf((float)a[1], (float)wc[1], sum));
#endif
    }

    sum += __shfl_xor(sum, 1);
    sum += __shfl_xor(sum, 2);

    if (sub == 0) out[e] = sum + b2[0];
}

// ---------------------------------------------------------------------------
extern "C" void kernel_launch(void* const* d_in, const int* in_sizes, int n_in,
                              void* d_out, int out_size, void* d_ws, size_t ws_size,
                              hipStream_t stream) {
    const float* z  = (const float*)d_in[0];
    const int*   eg = (const int*)d_in[1];
    const float* W1 = (const float*)d_in[2];
    const float* b1 = (const float*)d_in[3];
    const float* W2 = (const float*)d_in[4];
    const float* b2 = (const float*)d_in[5];
    float* out = (float*)d_out;

    const int nNodes = in_sizes[0] / 64;   // 100000
    const int E      = in_sizes[1] / 2;    // 1000000

    u16* wtab = (u16*)d_ws;                        // 16 KB frag table + W2
    u16* pq   = (u16*)d_ws + 16384;                // nNodes*128*2 = 25.6 MB

    build_wfrag<<<dim3(33), dim3(256), 0, stream>>>(W1, W2, wtab);

    dim3 gA((nNodes + 127) / 128);         // 4 waves x 32 nodes per block
    node_mfma<<<gA, dim3(256), 0, stream>>>(z, wtab, b1, pq, nNodes);

    long long tB = (long long)E * 4;       // 4 threads per edge
    dim3 gB((unsigned)((tB + 255) / 256));
    edge_mlp<<<gB, dim3(256), 0, stream>>>(eg, eg + E, pq, wtab + 8192, b2, out, E);
}